// Round 22
// baseline (529.899 us; speedup 1.0000x reference)
//
#include <hip/hip_runtime.h>
#include <hip/hip_bf16.h>
#include <stdint.h>

#define DEV __device__ __forceinline__

typedef unsigned short u16;
typedef __bf16 bf16x8 __attribute__((ext_vector_type(8)));
typedef float f32x4 __attribute__((ext_vector_type(4)));

DEV float b2f(u16 u) { return __uint_as_float(((uint32_t)u) << 16); }
DEV u16 f2b(float f) {
  uint32_t u = __float_as_uint(f);
  u += 0x7fffu + ((u >> 16) & 1u);   // RNE
  return (u16)(u >> 16);
}
DEV float sigm(float z) { return __builtin_amdgcn_rcpf(1.f + __expf(-z)); }

// async global->LDS 16B. LDS dest is wave-uniform base + lane*16.
DEV void async16(const void* g, void* l) {
  __builtin_amdgcn_global_load_lds(
      (const __attribute__((address_space(1))) uint32_t*)g,
      (__attribute__((address_space(3))) uint32_t*)l, 16, 0, 0);
}

// ---------------- fused weight prep for all 4 layers + wout ----------------
__global__ __launch_bounds__(256) void prep_all_kernel(
    const float* __restrict__ W0, const float* __restrict__ W1,
    const float* __restrict__ W2, const float* __restrict__ W3,
    const float* __restrict__ g0, const float* __restrict__ g1,
    const float* __restrict__ g2, const float* __restrict__ g3,
    const float* __restrict__ b0, const float* __restrict__ b1,
    const float* __restrict__ b2, const float* __restrict__ b3,
    const float* __restrict__ sb0, const float* __restrict__ sb1,
    const float* __restrict__ sb2, const float* __restrict__ sb3,
    const float* __restrict__ wout,
    u16* __restrict__ Wt0, u16* __restrict__ Wt1, u16* __restrict__ Wt2,
    u16* __restrict__ Wt3,
    float* __restrict__ Sc0, float* __restrict__ Sc1, float* __restrict__ Sc2,
    float* __restrict__ Sc3,
    float* __restrict__ Tc0, float* __restrict__ Tc1, float* __restrict__ Tc2,
    float* __restrict__ Tc3,
    u16* __restrict__ wob) {
  int b = blockIdx.x;
  if (b >= 2432) {  // wout: 64*128 = 8192 elems
    int i = (b - 2432) * 256 + threadIdx.x;
    wob[i] = f2b(wout[i]);
    return;
  }
  const float *W, *g, *bv, *sb;
  u16* Wt;
  float *scol, *tcol;
  int K, hid, kk, c;
  if (b < 768) {
    W = W0; g = g0; bv = b0; sb = sb0; Wt = Wt0; scol = Sc0; tcol = Tc0;
    K = 256; hid = 128; kk = 3; c = b;
  } else if (b < 1536) {
    W = W1; g = g1; bv = b1; sb = sb1; Wt = Wt1; scol = Sc1; tcol = Tc1;
    K = 256; hid = 128; kk = 3; c = b - 768;
  } else if (b < 2048) {
    W = W2; g = g2; bv = b2; sb = sb2; Wt = Wt2; scol = Sc2; tcol = Tc2;
    K = 256; hid = 64; kk = 4; c = b - 1536;
  } else {
    W = W3; g = g3; bv = b3; sb = sb3; Wt = Wt3; scol = Sc3; tcol = Tc3;
    K = 128; hid = 64; kk = 3; c = b - 2048;
  }
  int C = 2 * hid * kk;
  int d = c / (hid * kk);
  int rem = c - d * hid * kk;
  int h = rem / kk;
  int j = rem - h * kk;
  int cp = (d * kk + j) * hid + h;  // permuted col: planes (d, j, h)

  int k2 = threadIdx.x;
  float a = 0.f, t = 0.f;
  if (k2 < K) {
    float w = W[(long long)k2 * C + c];
    float gg = g[k2];
    a = gg * w;
    t = bv[k2] * w;
    Wt[(long long)cp * K + k2] = f2b(a);
  }
#pragma unroll
  for (int off = 32; off; off >>= 1) { a += __shfl_xor(a, off); t += __shfl_xor(t, off); }
  __shared__ float sa[4], stt[4];
  int wv = threadIdx.x >> 6, ln = threadIdx.x & 63;
  if (ln == 0 && k2 < K) { sa[wv] = a; stt[wv] = t; }
  __syncthreads();
  if (threadIdx.x == 0) {
    float A = 0.f, T = 0.f;
    int nw = K >> 6;
    for (int i = 0; i < nw; ++i) { A += sa[i]; T += stt[i]; }
    float badd = 0.f;
    if (j == 1) badd = sb[2 * (d * hid + h)];
    else if (j == 2) badd = sb[2 * (d * hid + h) + 1];
    scol[cp] = A;
    tcol[cp] = T + badd;
  }
}

// ---------------- embedding + LN(ng,nb) -> bf16, (n,t) row layout ----------------
__global__ __launch_bounds__(256) void emb_kernel(const int* __restrict__ x,
                                                  const float* __restrict__ emb,
                                                  const float* __restrict__ ng,
                                                  const float* __restrict__ nb,
                                                  u16* __restrict__ out) {
  int row = blockIdx.x * 4 + (threadIdx.x >> 6);  // row = n*512 + t
  int lane = threadIdx.x & 63;
  int tok = x[(row & 511) * 256 + (row >> 9)];    // x is (t, n)
  float4 v = *(const float4*)&emb[(long long)tok * 256 + lane * 4];
  float s = v.x + v.y + v.z + v.w;
  float sq = v.x * v.x + v.y * v.y + v.z * v.z + v.w * v.w;
#pragma unroll
  for (int off = 32; off; off >>= 1) { s += __shfl_xor(s, off); sq += __shfl_xor(sq, off); }
  float m = s * (1.f / 256.f);
  float var = fmaxf(sq * (1.f / 256.f) - m * m, 0.f);
  float rstd = rsqrtf(var + 1e-5f);
  float4 g = *(const float4*)&ng[lane * 4];
  float4 b = *(const float4*)&nb[lane * 4];
  ushort4 o;
  o.x = f2b((v.x - m) * rstd * g.x + b.x);
  o.y = f2b((v.y - m) * rstd * g.y + b.y);
  o.z = f2b((v.z - m) * rstd * g.z + b.z);
  o.w = f2b((v.w - m) * rstd * g.w + b.w);
  *(ushort4*)&out[(long long)row * 256 + lane * 4] = o;
}

// ---------------- fused LN+GEMM+scan per layer (TT=16, 2 blocks/CU) ----------------
// 512 threads / (n,dir) block. TT=16 t-steps/tile, NT=32. Xs ring-3. Ut transposed,
// double-buffered, TTP=18: row stride 9 dwords, gcd(9,32)=1 -> all Ut u32 accesses
// are conflict-free (2 lanes/bank). All Ut 8B accesses split into aligned u32 pairs.
template <int KK, int LOGH, int K, int GW, int MT, int SB, int ST>
__global__ __launch_bounds__(512, 2) void fused_layer_kernel(
    const u16* __restrict__ X, const u16* __restrict__ Wt,
    const float* __restrict__ scol, const float* __restrict__ tcol,
    const float* __restrict__ gln, const float* __restrict__ bln,
    const float* __restrict__ vv, u16* __restrict__ H) {
  constexpr int T = 512, TT = 16, NT = 32;
  constexpr int HID = 1 << LOGH;
  constexpr int DO = 2 * HID;
  constexpr int NC = KK * HID;
  constexpr int KST = K / 32;
  constexpr int GR = K / 8;      // 16B granules per X row
  constexpr int SL = TT * GR;    // 16B slots per X tile
  constexpr int TTP = 18;        // padded t-dim: 9-dword rows, gcd(9,32)=1
  constexpr int TPR = ST / TT;   // stats threads per row
  constexpr int GP = GR / TPR;   // granules per stats thread
  constexpr int QH = HID / (8 * TPR);  // res granules per stats thread
  static_assert(GW * MT * 16 == NC, "tile coverage");

  __shared__ u16 Xs[3][TT * GR * 8];
  __shared__ u16 Ut[2][4][HID][TTP];
  __shared__ float2 Sst[4][TT];

  const int tid = threadIdx.x;
  const int lane = tid & 63, wid = tid >> 6;
  const int la = lane & 15, lq = lane >> 4;
  const int d = blockIdx.x >> 8;     // uniform per block
  const int n = blockIdx.x & 255;
  const int cp0 = d * NC;
  const size_t xr0 = (size_t)n * T;

  const bool is_scan = (tid < HID);
  const bool is_gemm = (wid >= 2 && wid < 2 + GW);
  const bool is_stage = (wid == 2 || wid == 3);
  const bool is_stats = (tid >= SB) && (tid < SB + ST);

  // ---- GEMM persistent: B fragments + per-col scol/tcol ----
  bf16x8 Bf[MT][KST];
  float scv[MT], tcv[MT];
  const int nt0 = (wid - 2) * MT;
  if (is_gemm) {
#pragma unroll
    for (int j = 0; j < MT; ++j) {
      int cg = cp0 + (nt0 + j) * 16 + la;
      scv[j] = scol[cg];
      tcv[j] = tcol[cg];
#pragma unroll
      for (int kt = 0; kt < KST; ++kt)
        Bf[j][kt] = *(const bf16x8*)&Wt[(size_t)cg * K + kt * 32 + lq * 8];
    }
  }
  // ---- scan persistent ----
  float vf = 0.f, vr = 0.f, gc = 1.f, bc = 0.f, c = 0.f;
  int col = 0;
  if (is_scan) {
    col = d * HID + tid;
    vf = vv[2 * col];
    vr = vv[2 * col + 1];
    if (KK == 3) { gc = gln[col]; bc = bln[col]; }
  }

  auto do_stats = [&](int tt) {
    const u16* xq = &Xs[tt % 3][0];
    int u = tid - SB;
    int ro = u / TPR, part = u % TPR;
    float s1 = 0.f, s2 = 0.f;
#pragma unroll
    for (int q = 0; q < GP; ++q) {
      int qq = q * TPR + part;
      bf16x8 v = *(const bf16x8*)&xq[(ro * GR + (qq ^ (ro & 7))) * 8];
#pragma unroll
      for (int e = 0; e < 8; ++e) { float f = (float)v[e]; s1 += f; s2 = fmaf(f, f, s2); }
    }
#pragma unroll
    for (int off = 1; off < TPR; off <<= 1) { s1 += __shfl_xor(s1, off); s2 += __shfl_xor(s2, off); }
    if (part == 0) {
      constexpr float rk = 1.f / (float)K;
      float m = s1 * rk;
      float rs = rsqrtf(fmaxf(s2 * rk - m * m, 0.f) + 1e-5f);
      Sst[tt & 3][ro] = make_float2(m, rs);
    }
  };

  auto do_res = [&](int g) {  // KK==3 only: plane 3 = normalized X column values
    int u = tid - SB;
    int ro = u / TPR, part = u % TPR;
    float2 st = Sst[g & 3][ro];
    const u16* xq = &Xs[g % 3][0];
    u16* rp = &Ut[g & 1][3][0][0];
    for (int q = d * QH; q < (d + 1) * QH; ++q) {
      int qq = q * TPR + part;
      bf16x8 v = *(const bf16x8*)&xq[(ro * GR + (qq ^ (ro & 7))) * 8];
      int c0 = qq * 8 - d * HID;
#pragma unroll
      for (int e = 0; e < 8; ++e)
        rp[(c0 + e) * TTP + ro] = f2b(((float)v[e] - st.x) * st.y);
    }
  };

#define STAGE_X(G)                                                          \
  {                                                                         \
    int b3_ = (G) % 3;                                                      \
    int rb_ = d ? (T - ((G) + 1) * TT) : (G) * TT;                          \
    const char* s0_ = (const char*)(X + (xr0 + rb_) * K);                   \
    char* dl_ = (char*)&Xs[b3_][0];                                         \
    int st_ = tid - 128;                                                    \
    _Pragma("unroll") for (int i_ = 0; i_ < SL / 128; ++i_) {               \
      int u_ = i_ * 128 + st_;                                              \
      int row_ = u_ / GR, q_ = u_ % GR;                                     \
      async16(s0_ + (size_t)row_ * (K * 2) + ((q_ ^ (row_ & 7)) << 4),      \
              dl_ + i_ * 2048 + (wid - 2) * 1024);                          \
    }                                                                       \
  }

#define SSTEP(TL, TGLOB) {                                                  \
    uint32_t w0 = sv[0][(TL) >> 1];                                         \
    uint32_t w1 = sv[1][(TL) >> 1];                                         \
    uint32_t w2 = sv[2][(TL) >> 1];                                         \
    uint32_t w3 = sv[3][(TL) >> 1];                                         \
    float xt = __uint_as_float(((TL) & 1) ? (w0 & 0xFFFF0000u) : (w0 << 16)); \
    float fk = __uint_as_float(((TL) & 1) ? (w1 & 0xFFFF0000u) : (w1 << 16)); \
    float rk2 = __uint_as_float(((TL) & 1) ? (w2 & 0xFFFF0000u) : (w2 << 16)); \
    float rsv = __uint_as_float(((TL) & 1) ? (w3 & 0xFFFF0000u) : (w3 << 16)); \
    float res = fmaf(rsv, gc, bc);                                          \
    float f = sigm(fmaf(vf, c, fk));                                        \
    float c2 = fmaf(f, c - xt, xt);                                         \
    float rg2 = sigm(fmaf(vr, c, rk2));                                     \
    float hh = fmaf(rg2, fmaxf(c2, 0.f) - res, res);                        \
    c = c2;                                                                 \
    Hb[(size_t)(TGLOB) * DO] = f2b(hh); }

  if (is_stage) { STAGE_X(0); STAGE_X(1); }
  __syncthreads();
  if (is_stats) do_stats(0);
  __syncthreads();

  for (int g = 0; g <= NT; ++g) {
    // ---- GEMM on tile g (16 rows) ----
    if (g < NT && is_gemm) {
      if (is_stage && g + 2 < NT) STAGE_X(g + 2);
      const u16* xp = &Xs[g % 3][0];
      f32x4 acc[MT] = {};
#pragma unroll
      for (int kt = 0; kt < KST; ++kt) {
        bf16x8 a0;
        {
          int r0 = la;
          a0 = *(const bf16x8*)&xp[(r0 * GR + ((kt * 4 + lq) ^ (r0 & 7))) * 8];
        }
#pragma unroll
        for (int j = 0; j < MT; ++j)
          acc[j] = __builtin_amdgcn_mfma_f32_16x16x32_bf16(a0, Bf[j][kt], acc[j], 0, 0, 0);
      }
      float2 st2[4];
#pragma unroll
      for (int rg = 0; rg < 4; ++rg) st2[rg] = Sst[g & 3][lq * 4 + rg];
#pragma unroll
      for (int j = 0; j < MT; ++j) {
        int colg_l = (nt0 + j) * 16 + la;
        int plane = colg_l >> LOGH, hc = colg_l & (HID - 1);
        float uv[4];
#pragma unroll
        for (int rg = 0; rg < 4; ++rg) {
          float2 st = st2[rg];
          uv[rg] = fmaf(st.y, acc[j][rg], fmaf(-st.x * st.y, scv[j], tcv[j]));
        }
        u16* up = &Ut[g & 1][plane][hc][lq * 4];
        *(uint32_t*)&up[0] = (uint32_t)f2b(uv[0]) | ((uint32_t)f2b(uv[1]) << 16);
        *(uint32_t*)&up[2] = (uint32_t)f2b(uv[2]) | ((uint32_t)f2b(uv[3]) << 16);
      }
    }
    // ---- scan prefetch (first half: 8 steps, 4 u32/plane) ----
    uint32_t sv[4][4];
    if (g >= 1 && is_scan) {
      const int ub = (g - 1) & 1;
      const int h0 = d ? 1 : 0;
#pragma unroll
      for (int p = 0; p < 4; ++p)
#pragma unroll
        for (int q = 0; q < 4; ++q)
          sv[p][q] = *(const uint32_t*)&Ut[ub][p][tid][h0 * 8 + q * 2];
    }
    // ---- stats (tile g+1) + res (tile g) ----
    if (is_stats) {
      if (g + 1 < NT) do_stats(g + 1);
      if (KK == 3 && g < NT) do_res(g);
    }
    // ---- scan chain (register-only, 16 steps) ----
    if (g >= 1 && is_scan) {
      const int tg = g - 1, ub = tg & 1;
      const int rb = d ? (T - (tg + 1) * TT) : tg * TT;
      u16* Hb = H + (xr0 + rb) * DO + col;
      if (d == 0) {
#pragma unroll
        for (int tl = 0; tl < 8; ++tl) SSTEP(tl, tl)
#pragma unroll
        for (int p = 0; p < 4; ++p)
#pragma unroll
          for (int q = 0; q < 4; ++q)
            sv[p][q] = *(const uint32_t*)&Ut[ub][p][tid][8 + q * 2];
#pragma unroll
        for (int tl = 0; tl < 8; ++tl) SSTEP(tl, 8 + tl)
      } else {
#pragma unroll
        for (int i = 0; i < 8; ++i) SSTEP(7 - i, 8 + (7 - i))
#pragma unroll
        for (int p = 0; p < 4; ++p)
#pragma unroll
          for (int q = 0; q < 4; ++q)
            sv[p][q] = *(const uint32_t*)&Ut[ub][p][tid][q * 2];
#pragma unroll
        for (int i = 0; i < 8; ++i) SSTEP(7 - i, 7 - i)
      }
    }
    __syncthreads();
  }
#undef STAGE_X
#undef SSTEP
}

// ---------------- final projection: out[r, :] = h4[r, :] @ wout^T + bout (f32 out) ------
__global__ __launch_bounds__(256) void outgemm_kernel(const u16* __restrict__ h4,
                                                      const u16* __restrict__ wob,
                                                      const float* __restrict__ bout,
                                                      float* __restrict__ out) {
  __shared__ u16 As[128 * 128];  // 32 KiB
  int tid = threadIdx.x;
  int lane = tid & 63, wid = tid >> 6;
  int la = lane & 15, lq = lane >> 4;
  long long m0 = (long long)blockIdx.x * 128;

#pragma unroll
  for (int it = 0; it < 8; ++it) {
    int u = it * 256 + tid;
    int row = u >> 4, q = u & 15;
    const char* src = (const char*)h4 + (m0 + row) * 256 + ((q ^ (row & 7)) << 4);
    async16(src, (char*)As + it * 4096 + wid * 1024);
  }
  bf16x8 bfr[4][4];
#pragma unroll
  for (int nf = 0; nf < 4; ++nf)
#pragma unroll
    for (int ks = 0; ks < 4; ++ks)
      bfr[nf][ks] = *(const bf16x8*)&wob[(nf * 16 + la) * 128 + ks * 32 + lq * 8];
  __syncthreads();

  f32x4 acc[2][4] = {};
#pragma unroll
  for (int ks = 0; ks < 4; ++ks) {
#pragma unroll
    for (int mf = 0; mf < 2; ++mf) {
      int row = wid * 32 + mf * 16 + la;
      bf16x8 a = *(const bf16x8*)&As[row * 128 + (((ks * 4 + lq) ^ (row & 7)) << 3)];
#pragma unroll
      for (int nf = 0; nf < 4; ++nf)
        acc[mf][nf] = __builtin_amdgcn_mfma_f32_16x16x32_bf16(a, bfr[nf][ks], acc[mf][nf], 0, 0, 0);
    }
  }
#pragma unroll
  for (int mf = 0; mf < 2; ++mf)
#pragma unroll
    for (int nf = 0; nf < 4; ++nf) {
      int colg = nf * 16 + la;
      float bo = bout[colg];
#pragma unroll
      for (int reg = 0; reg < 4; ++reg) {
        long long r = m0 + wid * 32 + mf * 16 + lq * 4 + reg;
        out[r * 64 + colg] = acc[mf][nf][reg] + bo;
      }
    }
}

// ---------------- launch ----------------
extern "C" void kernel_launch(void* const* d_in, const int* in_sizes, int n_in,
                              void* d_out, int out_size, void* d_ws, size_t ws_size,
                              hipStream_t stream) {
  const int* x = (const int*)d_in[0];
  const float* emb = (const float*)d_in[1];
  const float* ng = (const float*)d_in[2];
  const float* nb = (const float*)d_in[3];
  const float* W[4] = {(const float*)d_in[4], (const float*)d_in[9], (const float*)d_in[14],
                       (const float*)d_in[19]};
  const float* Vv[4] = {(const float*)d_in[5], (const float*)d_in[10], (const float*)d_in[15],
                        (const float*)d_in[20]};
  const float* Bv[4] = {(const float*)d_in[6], (const float*)d_in[11], (const float*)d_in[16],
                        (const float*)d_in[21]};
  const float* G[4] = {(const float*)d_in[7], (const float*)d_in[12], (const float*)d_in[17],
                       (const float*)d_in[22]};
  const float* Bt[4] = {(const float*)d_in[8], (const float*)d_in[13], (const float*)d_in[18],
                        (const float*)d_in[23]};
  const float* wout = (const float*)d_in[24];
  const float* bout = (const float*)d_in[25];
  float* out = (float*)d_out;

  char* ws = (char*)d_ws;
  u16* XA = (u16*)ws;                       // 64 MiB ping
  u16* XB = (u16*)(ws + 67108864);          // 64 MiB pong
  char* p = ws + 134217728;
  u16* Wt[4];
  float* Sc[4];
  float* Tc[4];
  int Kd[4] = {256, 256, 256, 128};
  int Hd[4] = {128, 128, 64, 64};
  int kkv[4] = {3, 3, 4, 3};
  for (int i = 0; i < 4; ++i) {
    int C = 2 * Hd[i] * kkv[i];
    Wt[i] = (u16*)p; p += (size_t)C * Kd[i] * 2;
    Sc[i] = (float*)p; p += (size_t)C * 4;
    Tc[i] = (float*)p; p += (size_t)C * 4;
  }
  u16* wob = (u16*)p;

  prep_all_kernel<<<dim3(2464), dim3(256), 0, stream>>>(
      W[0], W[1], W[2], W[3], G[0], G[1], G[2], G[3], Bt[0], Bt[1], Bt[2], Bt[3],
      Bv[0], Bv[1], Bv[2], Bv[3], wout,
      Wt[0], Wt[1], Wt[2], Wt[3], Sc[0], Sc[1], Sc[2], Sc[3], Tc[0], Tc[1], Tc[2], Tc[3],
      wob);
  emb_kernel<<<dim3(32768), dim3(256), 0, stream>>>(x, emb, ng, nb, XA);

  // L1: XA -> XB  (K=256, HID=128, kk=3): NC=384 = 6 waves * 4 tiles; stats on scan waves
  fused_layer_kernel<3, 7, 256, 6, 4, 0, 128><<<dim3(512), dim3(512), 0, stream>>>(
      XA, Wt[0], Sc[0], Tc[0], G[0], Bt[0], Vv[0], XB);
  // L2: XB -> XA
  fused_layer_kernel<3, 7, 256, 6, 4, 0, 128><<<dim3(512), dim3(512), 0, stream>>>(
      XB, Wt[1], Sc[1], Tc[1], G[1], Bt[1], Vv[1], XA);
  // L3: XA -> XB  (K=256, HID=64, kk=4): NC=256 = 4 waves * 4 tiles, stats waves 6-7
  fused_layer_kernel<4, 6, 256, 4, 4, 384, 128><<<dim3(512), dim3(512), 0, stream>>>(
      XA, Wt[2], Sc[2], Tc[2], G[2], Bt[2], Vv[2], XB);
  // L4: XB -> XA  (K=128, HID=64, kk=3): NC=192 = 6 waves * 2 tiles; stats on scan waves
  fused_layer_kernel<3, 6, 128, 6, 2, 0, 64><<<dim3(512), dim3(512), 0, stream>>>(
      XB, Wt[3], Sc[3], Tc[3], G[3], Bt[3], Vv[3], XA);
  // output projection
  outgemm_kernel<<<dim3(1024), dim3(256), 0, stream>>>(XA, wob, bout, out);
}

// Round 23
// 523.512 us; speedup vs baseline: 1.0122x; 1.0122x over previous
//
#include <hip/hip_runtime.h>
#include <hip/hip_bf16.h>
#include <stdint.h>

#define DEV __device__ __forceinline__

typedef unsigned short u16;
typedef __bf16 bf16x8 __attribute__((ext_vector_type(8)));
typedef float f32x4 __attribute__((ext_vector_type(4)));

DEV float b2f(u16 u) { return __uint_as_float(((uint32_t)u) << 16); }
DEV u16 f2b(float f) {
  uint32_t u = __float_as_uint(f);
  u += 0x7fffu + ((u >> 16) & 1u);   // RNE
  return (u16)(u >> 16);
}
DEV float sigm(float z) { return __builtin_amdgcn_rcpf(1.f + __expf(-z)); }

// async global->LDS 16B. LDS dest is wave-uniform base + lane*16.
DEV void async16(const void* g, void* l) {
  __builtin_amdgcn_global_load_lds(
      (const __attribute__((address_space(1))) uint32_t*)g,
      (__attribute__((address_space(3))) uint32_t*)l, 16, 0, 0);
}

// ---------------- fused weight prep for all 4 layers + wout ----------------
__global__ __launch_bounds__(256) void prep_all_kernel(
    const float* __restrict__ W0, const float* __restrict__ W1,
    const float* __restrict__ W2, const float* __restrict__ W3,
    const float* __restrict__ g0, const float* __restrict__ g1,
    const float* __restrict__ g2, const float* __restrict__ g3,
    const float* __restrict__ b0, const float* __restrict__ b1,
    const float* __restrict__ b2, const float* __restrict__ b3,
    const float* __restrict__ sb0, const float* __restrict__ sb1,
    const float* __restrict__ sb2, const float* __restrict__ sb3,
    const float* __restrict__ wout,
    u16* __restrict__ Wt0, u16* __restrict__ Wt1, u16* __restrict__ Wt2,
    u16* __restrict__ Wt3,
    float* __restrict__ Sc0, float* __restrict__ Sc1, float* __restrict__ Sc2,
    float* __restrict__ Sc3,
    float* __restrict__ Tc0, float* __restrict__ Tc1, float* __restrict__ Tc2,
    float* __restrict__ Tc3,
    u16* __restrict__ wob) {
  int b = blockIdx.x;
  if (b >= 2432) {  // wout: 64*128 = 8192 elems
    int i = (b - 2432) * 256 + threadIdx.x;
    wob[i] = f2b(wout[i]);
    return;
  }
  const float *W, *g, *bv, *sb;
  u16* Wt;
  float *scol, *tcol;
  int K, hid, kk, c;
  if (b < 768) {
    W = W0; g = g0; bv = b0; sb = sb0; Wt = Wt0; scol = Sc0; tcol = Tc0;
    K = 256; hid = 128; kk = 3; c = b;
  } else if (b < 1536) {
    W = W1; g = g1; bv = b1; sb = sb1; Wt = Wt1; scol = Sc1; tcol = Tc1;
    K = 256; hid = 128; kk = 3; c = b - 768;
  } else if (b < 2048) {
    W = W2; g = g2; bv = b2; sb = sb2; Wt = Wt2; scol = Sc2; tcol = Tc2;
    K = 256; hid = 64; kk = 4; c = b - 1536;
  } else {
    W = W3; g = g3; bv = b3; sb = sb3; Wt = Wt3; scol = Sc3; tcol = Tc3;
    K = 128; hid = 64; kk = 3; c = b - 2048;
  }
  int C = 2 * hid * kk;
  int d = c / (hid * kk);
  int rem = c - d * hid * kk;
  int h = rem / kk;
  int j = rem - h * kk;
  int cp = (d * kk + j) * hid + h;  // permuted col: planes (d, j, h)

  int k2 = threadIdx.x;
  float a = 0.f, t = 0.f;
  if (k2 < K) {
    float w = W[(long long)k2 * C + c];
    float gg = g[k2];
    a = gg * w;
    t = bv[k2] * w;
    Wt[(long long)cp * K + k2] = f2b(a);
  }
#pragma unroll
  for (int off = 32; off; off >>= 1) { a += __shfl_xor(a, off); t += __shfl_xor(t, off); }
  __shared__ float sa[4], stt[4];
  int wv = threadIdx.x >> 6, ln = threadIdx.x & 63;
  if (ln == 0 && k2 < K) { sa[wv] = a; stt[wv] = t; }
  __syncthreads();
  if (threadIdx.x == 0) {
    float A = 0.f, T = 0.f;
    int nw = K >> 6;
    for (int i = 0; i < nw; ++i) { A += sa[i]; T += stt[i]; }
    float badd = 0.f;
    if (j == 1) badd = sb[2 * (d * hid + h)];
    else if (j == 2) badd = sb[2 * (d * hid + h) + 1];
    scol[cp] = A;
    tcol[cp] = T + badd;
  }
}

// ---------------- embedding + LN(ng,nb) -> bf16, (n,t) row layout ----------------
__global__ __launch_bounds__(256) void emb_kernel(const int* __restrict__ x,
                                                  const float* __restrict__ emb,
                                                  const float* __restrict__ ng,
                                                  const float* __restrict__ nb,
                                                  u16* __restrict__ out) {
  int row = blockIdx.x * 4 + (threadIdx.x >> 6);  // row = n*512 + t
  int lane = threadIdx.x & 63;
  int tok = x[(row & 511) * 256 + (row >> 9)];    // x is (t, n)
  float4 v = *(const float4*)&emb[(long long)tok * 256 + lane * 4];
  float s = v.x + v.y + v.z + v.w;
  float sq = v.x * v.x + v.y * v.y + v.z * v.z + v.w * v.w;
#pragma unroll
  for (int off = 32; off; off >>= 1) { s += __shfl_xor(s, off); sq += __shfl_xor(sq, off); }
  float m = s * (1.f / 256.f);
  float var = fmaxf(sq * (1.f / 256.f) - m * m, 0.f);
  float rstd = rsqrtf(var + 1e-5f);
  float4 g = *(const float4*)&ng[lane * 4];
  float4 b = *(const float4*)&nb[lane * 4];
  ushort4 o;
  o.x = f2b((v.x - m) * rstd * g.x + b.x);
  o.y = f2b((v.y - m) * rstd * g.y + b.y);
  o.z = f2b((v.z - m) * rstd * g.z + b.z);
  o.w = f2b((v.w - m) * rstd * g.w + b.w);
  *(ushort4*)&out[(long long)row * 256 + lane * 4] = o;
}

// ---------------- fused LN+GEMM+scan per layer (TT=16 -> 2 blocks/CU) ----------------
// 512 threads / (n,dir) block. LDS <= ~65KB so TWO blocks co-reside per CU: the second
// block's GEMM hides the first's serial scan + B-reload latency. TT=16 t-steps/tile,
// NT=32 tiles. Xs ring-3 (stage g+2 | stats g+1 | gemm+res g). Ut transposed, double-
// buffered, TTP=20 (8B-aligned rows, 2-way bank alias = free). Scan register-only.
template <int KK, int LOGH, int K, int GW, int MT, int SB, int ST>
__global__ __launch_bounds__(512, 2) void fused_layer_kernel(
    const u16* __restrict__ X, const u16* __restrict__ Wt,
    const float* __restrict__ scol, const float* __restrict__ tcol,
    const float* __restrict__ gln, const float* __restrict__ bln,
    const float* __restrict__ vv, u16* __restrict__ H) {
  constexpr int T = 512, TT = 16, NT = 32;
  constexpr int HID = 1 << LOGH;
  constexpr int DO = 2 * HID;
  constexpr int NC = KK * HID;
  constexpr int KST = K / 32;
  constexpr int GR = K / 8;      // 16B granules per X row
  constexpr int SL = TT * GR;    // 16B slots per X tile
  constexpr int TTP = 20;        // padded t-dim: 40B rows (8B aligned, 2-way alias ok)
  constexpr int TPR = ST / TT;   // stats threads per row
  constexpr int GP = GR / TPR;   // granules per stats thread
  constexpr int QH = HID / (8 * TPR);  // res granules per stats thread
  static_assert(GW * MT * 16 == NC, "tile coverage");

  __shared__ u16 Xs[3][TT * GR * 8];
  __shared__ u16 Ut[2][4][HID][TTP];
  __shared__ float2 Sst[4][TT];

  const int tid = threadIdx.x;
  const int lane = tid & 63, wid = tid >> 6;
  const int la = lane & 15, lq = lane >> 4;
  const int d = blockIdx.x >> 8;     // uniform per block
  const int n = blockIdx.x & 255;
  const int cp0 = d * NC;
  const size_t xr0 = (size_t)n * T;

  const bool is_scan = (tid < HID);
  const bool is_gemm = (wid >= 2 && wid < 2 + GW);
  const bool is_stage = (wid == 2 || wid == 3);
  const bool is_stats = (tid >= SB) && (tid < SB + ST);

  // ---- GEMM persistent: B fragments + per-col scol/tcol ----
  bf16x8 Bf[MT][KST];
  float scv[MT], tcv[MT];
  const int nt0 = (wid - 2) * MT;
  if (is_gemm) {
#pragma unroll
    for (int j = 0; j < MT; ++j) {
      int cg = cp0 + (nt0 + j) * 16 + la;
      scv[j] = scol[cg];
      tcv[j] = tcol[cg];
#pragma unroll
      for (int kt = 0; kt < KST; ++kt)
        Bf[j][kt] = *(const bf16x8*)&Wt[(size_t)cg * K + kt * 32 + lq * 8];
    }
  }
  // ---- scan persistent ----
  float vf = 0.f, vr = 0.f, gc = 1.f, bc = 0.f, c = 0.f;
  int col = 0;
  if (is_scan) {
    col = d * HID + tid;
    vf = vv[2 * col];
    vr = vv[2 * col + 1];
    if (KK == 3) { gc = gln[col]; bc = bln[col]; }
  }

  auto do_stats = [&](int tt) {
    const u16* xq = &Xs[tt % 3][0];
    int u = tid - SB;
    int ro = u / TPR, part = u % TPR;
    float s1 = 0.f, s2 = 0.f;
#pragma unroll
    for (int q = 0; q < GP; ++q) {
      int qq = q * TPR + part;
      bf16x8 v = *(const bf16x8*)&xq[(ro * GR + (qq ^ (ro & 7))) * 8];
#pragma unroll
      for (int e = 0; e < 8; ++e) { float f = (float)v[e]; s1 += f; s2 = fmaf(f, f, s2); }
    }
#pragma unroll
    for (int off = 1; off < TPR; off <<= 1) { s1 += __shfl_xor(s1, off); s2 += __shfl_xor(s2, off); }
    if (part == 0) {
      constexpr float rk = 1.f / (float)K;
      float m = s1 * rk;
      float rs = rsqrtf(fmaxf(s2 * rk - m * m, 0.f) + 1e-5f);
      Sst[tt & 3][ro] = make_float2(m, rs);
    }
  };

  auto do_res = [&](int g) {  // KK==3 only: plane 3 = normalized X column values
    int u = tid - SB;
    int ro = u / TPR, part = u % TPR;
    float2 st = Sst[g & 3][ro];
    const u16* xq = &Xs[g % 3][0];
    u16* rp = &Ut[g & 1][3][0][0];
    for (int q = d * QH; q < (d + 1) * QH; ++q) {
      int qq = q * TPR + part;
      bf16x8 v = *(const bf16x8*)&xq[(ro * GR + (qq ^ (ro & 7))) * 8];
      int c0 = qq * 8 - d * HID;
#pragma unroll
      for (int e = 0; e < 8; ++e)
        rp[(c0 + e) * TTP + ro] = f2b(((float)v[e] - st.x) * st.y);
    }
  };

#define STAGE_X(G)                                                          \
  {                                                                         \
    int b3_ = (G) % 3;                                                      \
    int rb_ = d ? (T - ((G) + 1) * TT) : (G) * TT;                          \
    const char* s0_ = (const char*)(X + (xr0 + rb_) * K);                   \
    char* dl_ = (char*)&Xs[b3_][0];                                         \
    int st_ = tid - 128;                                                    \
    _Pragma("unroll") for (int i_ = 0; i_ < SL / 128; ++i_) {               \
      int u_ = i_ * 128 + st_;                                              \
      int row_ = u_ / GR, q_ = u_ % GR;                                     \
      async16(s0_ + (size_t)row_ * (K * 2) + ((q_ ^ (row_ & 7)) << 4),      \
              dl_ + i_ * 2048 + (wid - 2) * 1024);                          \
    }                                                                       \
  }

#define SSTEP(TL, TGLOB) {                                                  \
    uint32_t w0 = ((TL) & 2) ? sv[0][(TL) >> 2].y : sv[0][(TL) >> 2].x;     \
    uint32_t w1 = ((TL) & 2) ? sv[1][(TL) >> 2].y : sv[1][(TL) >> 2].x;     \
    uint32_t w2 = ((TL) & 2) ? sv[2][(TL) >> 2].y : sv[2][(TL) >> 2].x;     \
    uint32_t w3 = ((TL) & 2) ? sv[3][(TL) >> 2].y : sv[3][(TL) >> 2].x;     \
    float xt = __uint_as_float(((TL) & 1) ? (w0 & 0xFFFF0000u) : (w0 << 16)); \
    float fk = __uint_as_float(((TL) & 1) ? (w1 & 0xFFFF0000u) : (w1 << 16)); \
    float rk2 = __uint_as_float(((TL) & 1) ? (w2 & 0xFFFF0000u) : (w2 << 16)); \
    float rsv = __uint_as_float(((TL) & 1) ? (w3 & 0xFFFF0000u) : (w3 << 16)); \
    float res = fmaf(rsv, gc, bc);                                          \
    float f = sigm(fmaf(vf, c, fk));                                        \
    float c2 = fmaf(f, c - xt, xt);                                         \
    float rg2 = sigm(fmaf(vr, c, rk2));                                     \
    float hh = fmaf(rg2, fmaxf(c2, 0.f) - res, res);                        \
    c = c2;                                                                 \
    Hb[(size_t)(TGLOB) * DO] = f2b(hh); }

  if (is_stage) { STAGE_X(0); STAGE_X(1); }
  __syncthreads();
  if (is_stats) do_stats(0);
  __syncthreads();

  for (int g = 0; g <= NT; ++g) {
    // ---- GEMM on tile g (16 rows) ----
    if (g < NT && is_gemm) {
      if (is_stage && g + 2 < NT) STAGE_X(g + 2);
      const u16* xp = &Xs[g % 3][0];
      f32x4 acc[MT] = {};
#pragma unroll
      for (int kt = 0; kt < KST; ++kt) {
        bf16x8 a0;
        {
          int r0 = la;
          a0 = *(const bf16x8*)&xp[(r0 * GR + ((kt * 4 + lq) ^ (r0 & 7))) * 8];
        }
#pragma unroll
        for (int j = 0; j < MT; ++j)
          acc[j] = __builtin_amdgcn_mfma_f32_16x16x32_bf16(a0, Bf[j][kt], acc[j], 0, 0, 0);
      }
      float2 st2[4];
#pragma unroll
      for (int rg = 0; rg < 4; ++rg) st2[rg] = Sst[g & 3][lq * 4 + rg];
#pragma unroll
      for (int j = 0; j < MT; ++j) {
        int colg_l = (nt0 + j) * 16 + la;
        int plane = colg_l >> LOGH, hc = colg_l & (HID - 1);
        float uv[4];
#pragma unroll
        for (int rg = 0; rg < 4; ++rg) {
          float2 st = st2[rg];
          uv[rg] = fmaf(st.y, acc[j][rg], fmaf(-st.x * st.y, scv[j], tcv[j]));
        }
        uint2 pk;
        pk.x = (uint32_t)f2b(uv[0]) | ((uint32_t)f2b(uv[1]) << 16);
        pk.y = (uint32_t)f2b(uv[2]) | ((uint32_t)f2b(uv[3]) << 16);
        *(uint2*)&Ut[g & 1][plane][hc][lq * 4] = pk;
      }
    }
    // ---- scan prefetch (first half: 8 steps) ----
    uint2 sv[4][2];
    if (g >= 1 && is_scan) {
      const int ub = (g - 1) & 1;
      const int h0 = d ? 1 : 0;
#pragma unroll
      for (int p = 0; p < 4; ++p)
#pragma unroll
        for (int q = 0; q < 2; ++q)
          sv[p][q] = *(const uint2*)&Ut[ub][p][tid][h0 * 8 + q * 4];
    }
    // ---- stats (tile g+1) + res (tile g) ----
    if (is_stats) {
      if (g + 1 < NT) do_stats(g + 1);
      if (KK == 3 && g < NT) do_res(g);
    }
    // ---- scan chain (register-only, 16 steps) ----
    if (g >= 1 && is_scan) {
      const int tg = g - 1, ub = tg & 1;
      const int rb = d ? (T - (tg + 1) * TT) : tg * TT;
      u16* Hb = H + (xr0 + rb) * DO + col;
      if (d == 0) {
#pragma unroll
        for (int tl = 0; tl < 8; ++tl) SSTEP(tl, tl)
#pragma unroll
        for (int p = 0; p < 4; ++p)
#pragma unroll
          for (int q = 0; q < 2; ++q)
            sv[p][q] = *(const uint2*)&Ut[ub][p][tid][8 + q * 4];
#pragma unroll
        for (int tl = 0; tl < 8; ++tl) SSTEP(tl, 8 + tl)
      } else {
#pragma unroll
        for (int i = 0; i < 8; ++i) SSTEP(7 - i, 8 + (7 - i))
#pragma unroll
        for (int p = 0; p < 4; ++p)
#pragma unroll
          for (int q = 0; q < 2; ++q)
            sv[p][q] = *(const uint2*)&Ut[ub][p][tid][q * 4];
#pragma unroll
        for (int i = 0; i < 8; ++i) SSTEP(7 - i, 7 - i)
      }
    }
    __syncthreads();
  }
#undef STAGE_X
#undef SSTEP
}

// ---------------- final projection: out[r, :] = h4[r, :] @ wout^T + bout (f32 out) ------
__global__ __launch_bounds__(256) void outgemm_kernel(const u16* __restrict__ h4,
                                                      const u16* __restrict__ wob,
                                                      const float* __restrict__ bout,
                                                      float* __restrict__ out) {
  __shared__ u16 As[128 * 128];  // 32 KiB
  int tid = threadIdx.x;
  int lane = tid & 63, wid = tid >> 6;
  int la = lane & 15, lq = lane >> 4;
  long long m0 = (long long)blockIdx.x * 128;

#pragma unroll
  for (int it = 0; it < 8; ++it) {
    int u = it * 256 + tid;
    int row = u >> 4, q = u & 15;
    const char* src = (const char*)h4 + (m0 + row) * 256 + ((q ^ (row & 7)) << 4);
    async16(src, (char*)As + it * 4096 + wid * 1024);
  }
  bf16x8 bfr[4][4];
#pragma unroll
  for (int nf = 0; nf < 4; ++nf)
#pragma unroll
    for (int ks = 0; ks < 4; ++ks)
      bfr[nf][ks] = *(const bf16x8*)&wob[(nf * 16 + la) * 128 + ks * 32 + lq * 8];
  __syncthreads();

  f32x4 acc[2][4] = {};
#pragma unroll
  for (int ks = 0; ks < 4; ++ks) {
#pragma unroll
    for (int mf = 0; mf < 2; ++mf) {
      int row = wid * 32 + mf * 16 + la;
      bf16x8 a = *(const bf16x8*)&As[row * 128 + (((ks * 4 + lq) ^ (row & 7)) << 3)];
#pragma unroll
      for (int nf = 0; nf < 4; ++nf)
        acc[mf][nf] = __builtin_amdgcn_mfma_f32_16x16x32_bf16(a, bfr[nf][ks], acc[mf][nf], 0, 0, 0);
    }
  }
#pragma unroll
  for (int mf = 0; mf < 2; ++mf)
#pragma unroll
    for (int nf = 0; nf < 4; ++nf) {
      int colg = nf * 16 + la;
      float bo = bout[colg];
#pragma unroll
      for (int reg = 0; reg < 4; ++reg) {
        long long r = m0 + wid * 32 + mf * 16 + lq * 4 + reg;
        out[r * 64 + colg] = acc[mf][nf][reg] + bo;
      }
    }
}

// ---------------- launch ----------------
extern "C" void kernel_launch(void* const* d_in, const int* in_sizes, int n_in,
                              void* d_out, int out_size, void* d_ws, size_t ws_size,
                              hipStream_t stream) {
  const int* x = (const int*)d_in[0];
  const float* emb = (const float*)d_in[1];
  const float* ng = (const float*)d_in[2];
  const float* nb = (const float*)d_in[3];
  const float* W[4] = {(const float*)d_in[4], (const float*)d_in[9], (const float*)d_in[14],
                       (const float*)d_in[19]};
  const float* Vv[4] = {(const float*)d_in[5], (const float*)d_in[10], (const float*)d_in[15],
                        (const float*)d_in[20]};
  const float* Bv[4] = {(const float*)d_in[6], (const float*)d_in[11], (const float*)d_in[16],
                        (const float*)d_in[21]};
  const float* G[4] = {(const float*)d_in[7], (const float*)d_in[12], (const float*)d_in[17],
                       (const float*)d_in[22]};
  const float* Bt[4] = {(const float*)d_in[8], (const float*)d_in[13], (const float*)d_in[18],
                        (const float*)d_in[23]};
  const float* wout = (const float*)d_in[24];
  const float* bout = (const float*)d_in[25];
  float* out = (float*)d_out;

  char* ws = (char*)d_ws;
  u16* XA = (u16*)ws;                       // 64 MiB ping
  u16* XB = (u16*)(ws + 67108864);          // 64 MiB pong
  char* p = ws + 134217728;
  u16* Wt[4];
  float* Sc[4];
  float* Tc[4];
  int Kd[4] = {256, 256, 256, 128};
  int Hd[4] = {128, 128, 64, 64};
  int kkv[4] = {3, 3, 4, 3};
  for (int i = 0; i < 4; ++i) {
    int C = 2 * Hd[i] * kkv[i];
    Wt[i] = (u16*)p; p += (size_t)C * Kd[i] * 2;
    Sc[i] = (float*)p; p += (size_t)C * 4;
    Tc[i] = (float*)p; p += (size_t)C * 4;
  }
  u16* wob = (u16*)p;

  prep_all_kernel<<<dim3(2464), dim3(256), 0, stream>>>(
      W[0], W[1], W[2], W[3], G[0], G[1], G[2], G[3], Bt[0], Bt[1], Bt[2], Bt[3],
      Bv[0], Bv[1], Bv[2], Bv[3], wout,
      Wt[0], Wt[1], Wt[2], Wt[3], Sc[0], Sc[1], Sc[2], Sc[3], Tc[0], Tc[1], Tc[2], Tc[3],
      wob);
  emb_kernel<<<dim3(32768), dim3(256), 0, stream>>>(x, emb, ng, nb, XA);

  // L1: XA -> XB  (K=256, HID=128, kk=3): NC=384 = 6 waves * 4 tiles; stats on scan waves
  fused_layer_kernel<3, 7, 256, 6, 4, 0, 128><<<dim3(512), dim3(512), 0, stream>>>(
      XA, Wt[0], Sc[0], Tc[0], G[0], Bt[0], Vv[0], XB);
  // L2: XB -> XA
  fused_layer_kernel<3, 7, 256, 6, 4, 0, 128><<<dim3(512), dim3(512), 0, stream>>>(
      XB, Wt[1], Sc[1], Tc[1], G[1], Bt[1], Vv[1], XA);
  // L3: XA -> XB  (K=256, HID=64, kk=4): NC=256 = 4 waves * 4 tiles, stats waves 6-7
  fused_layer_kernel<4, 6, 256, 4, 4, 384, 128><<<dim3(512), dim3(512), 0, stream>>>(
      XA, Wt[2], Sc[2], Tc[2], G[2], Bt[2], Vv[2], XB);
  // L4: XB -> XA  (K=128, HID=64, kk=3): NC=192 = 6 waves * 2 tiles; stats on scan waves
  fused_layer_kernel<3, 6, 128, 6, 2, 0, 64><<<dim3(512), dim3(512), 0, stream>>>(
      XB, Wt[3], Sc[3], Tc[3], G[3], Bt[3], Vv[3], XA);
  // output projection
  outgemm_kernel<<<dim3(1024), dim3(256), 0, stream>>>(XA, wob, bout, out);
}